// Round 10
// baseline (266.810 us; speedup 1.0000x reference)
//
#include <hip/hip_runtime.h>

#define DEVI __device__ __forceinline__

typedef unsigned short u16;
typedef unsigned int u32;

using bf16x8 = __attribute__((ext_vector_type(8))) short;
using f32x4  = __attribute__((ext_vector_type(4))) float;

DEVI u16 f2bf(float f) {
  u32 u = __builtin_bit_cast(u32, f);
  u32 r = (u + 0x7fffu + ((u >> 16) & 1u)) >> 16;
  return (u16)r;
}

DEVI void gl_lds16(const u16* g, u16* l) {
  __builtin_amdgcn_global_load_lds(
      (const __attribute__((address_space(1))) u32*)g,
      (__attribute__((address_space(3))) u32*)l, 16, 0, 0);
}

// ---------------- LayerNorm + bf16 cast, fused with weight transposes ----------------
__global__ __launch_bounds__(256) void ln_tr_kernel(
    const float* __restrict__ x, const float* __restrict__ lat,
    const float* __restrict__ gm, const float* __restrict__ bm,
    const float* __restrict__ gl, const float* __restrict__ bl,
    const float* __restrict__ Wq, const float* __restrict__ Wkv,
    const float* __restrict__ Wo,
    u16* __restrict__ kvin, u16* __restrict__ latb,
    u16* __restrict__ wqT, u16* __restrict__ wkvT, u16* __restrict__ woT)
{
  __shared__ float tshm[32][33];
  __shared__ float red[2][4];
  if (blockIdx.x >= 34816) {
    int t = blockIdx.x - 34816;       // 0..4095
    int bxg = t & 127, gy = t >> 7;   // 128 x 32
    const float* in; u16* outp; int C, bxi;
    if (bxg < 32)      { in = Wq;  outp = wqT;  C = 1024; bxi = bxg; }
    else if (bxg < 96) { in = Wkv; outp = wkvT; C = 2048; bxi = bxg - 32; }
    else               { in = Wo;  outp = woT;  C = 1024; bxi = bxg - 96; }
    int bx = bxi*32, by = gy*32;
    int tx = threadIdx.x & 31, ty = threadIdx.x >> 5;   // 32 x 8
    for (int k=0;k<32;k+=8) tshm[ty+k][tx] = in[(size_t)(by+ty+k)*C + bx+tx];
    __syncthreads();
    for (int k=0;k<32;k+=8) outp[(size_t)(bx+ty+k)*1024 + by+tx] = f2bf(tshm[tx][ty+k]);
    return;
  }
  int row = blockIdx.x;
  int bt = row / 1088, r = row % 1088;
  const float *src, *g, *b;
  bool is_lat = (r >= 1024);
  if (!is_lat) { src = x + ((size_t)bt*1024 + r)*1024; g = gm; b = bm; }
  else         { src = lat + ((size_t)bt*64 + (r-1024))*1024; g = gl; b = bl; }
  int tid = threadIdx.x;
  float4 v = *(const float4*)(src + tid*4);
  float s1 = v.x+v.y+v.z+v.w;
  float s2 = v.x*v.x+v.y*v.y+v.z*v.z+v.w*v.w;
  for (int off=32; off; off>>=1){ s1 += __shfl_down(s1,off); s2 += __shfl_down(s2,off); }
  int w = tid>>6, lane = tid&63;
  if (lane==0){ red[0][w]=s1; red[1][w]=s2; }
  __syncthreads();
  s1 = red[0][0]+red[0][1]+red[0][2]+red[0][3];
  s2 = red[1][0]+red[1][1]+red[1][2]+red[1][3];
  float mu = s1 * (1.f/1024.f);
  float var = s2 * (1.f/1024.f) - mu*mu;
  float rstd = rsqrtf(var + 1e-5f);
  float4 gv = *(const float4*)(g + tid*4);
  float4 bv = *(const float4*)(b + tid*4);
  ushort4 o;
  o.x = f2bf((v.x-mu)*rstd*gv.x + bv.x);
  o.y = f2bf((v.y-mu)*rstd*gv.y + bv.y);
  o.z = f2bf((v.z-mu)*rstd*gv.z + bv.z);
  o.w = f2bf((v.w-mu)*rstd*gv.w + bv.w);
  *(ushort4*)(kvin + (size_t)row*1024 + tid*4) = o;
  if (is_lat) *(ushort4*)(latb + ((size_t)(bt*64 + (r-1024)))*1024 + tid*4) = o;
}

// ---------------- persistent 256x256 4-phase bf16 GEMM: kv + q projections ----------------
// 1120 tiles (1088 kv + 32 q) over 256 persistent blocks (96 blocks x5, 160 x4).
// swz = (t&7)*140 + (t>>3), bijective; t+256 keeps t&7 -> same n-panel per block.
// Cross-tile pipelining: j=15's stage targets the NEXT tile's K-tile 0 --
// the prologue HBM fill is paid once per block, not once per tile.
__global__ __launch_bounds__(512,2) void gemm256_kvq(
    const u16* __restrict__ A, const u16* __restrict__ BT,
    const u16* __restrict__ Aq, const u16* __restrict__ BTq,
    u16* __restrict__ kb, u16* __restrict__ vt, u16* __restrict__ qb)
{
  __shared__ u16 lds[2][2][2][256][32];   // 128 KiB
  const int tid = threadIdx.x;
  const int w = tid>>6, lane = tid&63;
  const int li = lane&15, lg = lane>>4;
  const int wm = w>>2, wn = w&3;          // 2M x 4N waves
  const int bid = blockIdx.x;
  const int nt = (bid < 96) ? 5 : 4;      // 1120 = 96*5 + 160*4
  const int srow = lane>>2;
  const int scol = ((lane&3) ^ ((lane>>3)&3))*8;  // source-side T2 involution
  const int rchunk = (lg ^ ((li>>1)&3))*8;        // read-side (same involution)

#define RESOLVE(t, As, Bs, M0, N0, ISQ) do {                                  \
    int _swz = ((t)&7)*140 + ((t)>>3);                                        \
    if (_swz < 1088) { ISQ=false; As=A; Bs=BT; M0=(_swz>>3)*256; N0=(_swz&7)*256; } \
    else { ISQ=true; int _qt=_swz-1088; As=Aq; Bs=BTq; M0=(_qt>>2)*256; N0=(_qt&3)*256; } \
  } while(0)
#define STAGE(b, mat, kh, kt, SA, SB, M0_, N0_) do {                          \
    const u16* _s = (mat) ? (SB) : (SA);                                      \
    const int _base = (mat) ? (N0_) : (M0_);                                  \
    _Pragma("unroll")                                                         \
    for (int L=0; L<2; ++L) {                                                 \
      const int _r = L*128 + w*16;                                            \
      gl_lds16(_s + (size_t)(_base + _r + srow)*1024 + (kt)*64 + (kh)*32 + scol, \
               &lds[b][mat][kh][_r][0]);                                      \
    }                                                                         \
  } while(0)
#define BARRIER() asm volatile("s_barrier" ::: "memory")
#define LGKM0()   do { asm volatile("s_waitcnt lgkmcnt(0)" ::: "memory"); \
                       __builtin_amdgcn_sched_barrier(0); } while(0)
#define VM4()     asm volatile("s_waitcnt vmcnt(4)" ::: "memory")

  const u16 *Asrc, *Bsrc, *AsrcN, *BsrcN;
  int m0, n0, m0N, n0N; bool is_q, is_qN;
  RESOLVE(bid, Asrc, Bsrc, m0, n0, is_q);

  // prologue (once per block): stage tile0's K-tile 0 fully; wait kh0 half
  STAGE(0,0,0,0, Asrc,Bsrc,m0,n0); STAGE(0,1,0,0, Asrc,Bsrc,m0,n0);
  STAGE(0,0,1,0, Asrc,Bsrc,m0,n0); STAGE(0,1,1,0, Asrc,Bsrc,m0,n0);
  VM4(); BARRIER();

  for (int tk=0; tk<nt; ++tk) {
    const int tnext = (tk+1<nt) ? bid+(tk+1)*256 : bid+tk*256;  // self-dummy on last
    RESOLVE(tnext, AsrcN, BsrcN, m0N, n0N, is_qN);

    f32x4 acc[8][4] = {};
    for (int j=0; j<16; ++j) {
      const int c = j&1;
      const u16* sA = (j<15) ? Asrc : AsrcN;
      const u16* sB = (j<15) ? Bsrc : BsrcN;
      const int bM = (j<15) ? m0 : m0N;
      const int bN = (j<15) ? n0 : n0N;
      const int kt = (j<15) ? j+1 : 0;
      bf16x8 a[4], b0[4], b1[4];

      // ---- phase 0: kh0, mh0 ----
      #pragma unroll
      for (int mf=0; mf<4; ++mf)
        a[mf] = *(const bf16x8*)&lds[c][0][0][wm*128 + mf*16 + li][rchunk];
      #pragma unroll
      for (int nf=0; nf<4; ++nf)
        b0[nf] = *(const bf16x8*)&lds[c][1][0][wn*64 + nf*16 + li][rchunk];
      STAGE(c^1,0,0,kt, sA,sB,bM,bN);
      BARRIER(); LGKM0();
      __builtin_amdgcn_s_setprio(1);
      #pragma unroll
      for (int mf=0; mf<4; ++mf)
        #pragma unroll
        for (int nf=0; nf<4; ++nf)
          acc[mf][nf] = __builtin_amdgcn_mfma_f32_16x16x32_bf16(a[mf], b0[nf], acc[mf][nf], 0,0,0);
      __builtin_amdgcn_s_setprio(0);
      BARRIER();

      // ---- phase 1: kh0, mh1 ----
      #pragma unroll
      for (int mf=0; mf<4; ++mf)
        a[mf] = *(const bf16x8*)&lds[c][0][0][wm*128 + 64 + mf*16 + li][rchunk];
      STAGE(c^1,1,0,kt, sA,sB,bM,bN);
      VM4();
      BARRIER(); LGKM0();
      __builtin_amdgcn_s_setprio(1);
      #pragma unroll
      for (int mf=0; mf<4; ++mf)
        #pragma unroll
        for (int nf=0; nf<4; ++nf)
          acc[4+mf][nf] = __builtin_amdgcn_mfma_f32_16x16x32_bf16(a[mf], b0[nf], acc[4+mf][nf], 0,0,0);
      __builtin_amdgcn_s_setprio(0);
      BARRIER();

      // ---- phase 2: kh1, mh0 ----
      #pragma unroll
      for (int mf=0; mf<4; ++mf)
        a[mf] = *(const bf16x8*)&lds[c][0][1][wm*128 + mf*16 + li][rchunk];
      #pragma unroll
      for (int nf=0; nf<4; ++nf)
        b1[nf] = *(const bf16x8*)&lds[c][1][1][wn*64 + nf*16 + li][rchunk];
      STAGE(c^1,0,1,kt, sA,sB,bM,bN);
      BARRIER(); LGKM0();
      __builtin_amdgcn_s_setprio(1);
      #pragma unroll
      for (int mf=0; mf<4; ++mf)
        #pragma unroll
        for (int nf=0; nf<4; ++nf)
          acc[mf][nf] = __builtin_amdgcn_mfma_f32_16x16x32_bf16(a[mf], b1[nf], acc[mf][nf], 0,0,0);
      __builtin_amdgcn_s_setprio(0);
      BARRIER();

      // ---- phase 3: kh1, mh1 ----
      #pragma unroll
      for (int mf=0; mf<4; ++mf)
        a[mf] = *(const bf16x8*)&lds[c][0][1][wm*128 + 64 + mf*16 + li][rchunk];
      STAGE(c^1,1,1,kt, sA,sB,bM,bN);
      VM4();
      BARRIER(); LGKM0();
      __builtin_amdgcn_s_setprio(1);
      #pragma unroll
      for (int mf=0; mf<4; ++mf)
        #pragma unroll
        for (int nf=0; nf<4; ++nf)
          acc[4+mf][nf] = __builtin_amdgcn_mfma_f32_16x16x32_bf16(a[mf], b1[nf], acc[4+mf][nf], 0,0,0);
      __builtin_amdgcn_s_setprio(0);
      BARRIER();
    }

    // epilogue for current tile (static acc indices; uniform branches only)
    if (is_q) {
      #pragma unroll
      for (int am=0; am<8; ++am)
        #pragma unroll
        for (int nf=0; nf<4; ++nf) {
          int row = m0 + wm*128 + am*16 + lg*4;
          int col = n0 + wn*64 + nf*16 + li;
          #pragma unroll
          for (int rg=0; rg<4; ++rg)
            qb[(size_t)(row+rg)*1024 + col] = f2bf(acc[am][nf][rg]*0.125f);
        }
    } else if (n0 < 1024) {
      #pragma unroll
      for (int am=0; am<8; ++am)
        #pragma unroll
        for (int nf=0; nf<4; ++nf) {
          int row = m0 + wm*128 + am*16 + lg*4;
          int col = n0 + wn*64 + nf*16 + li;
          #pragma unroll
          for (int rg=0; rg<4; ++rg)
            kb[(size_t)(row+rg)*1024 + col] = f2bf(acc[am][nf][rg]);
        }
    } else {
      #pragma unroll
      for (int am=0; am<8; ++am)
        #pragma unroll
        for (int nf=0; nf<4; ++nf) {
          int r0 = m0 + wm*128 + am*16 + lg*4;
          int cc = n0 + wn*64 + nf*16 + li - 1024;
          int bt = r0/1088, jj = r0 - bt*1088;
          ushort4 o;
          o.x = f2bf(acc[am][nf][0]); o.y = f2bf(acc[am][nf][1]);
          o.z = f2bf(acc[am][nf][2]); o.w = f2bf(acc[am][nf][3]);
          *(ushort4*)(vt + ((size_t)(bt*1024 + cc))*1088 + jj) = o;
        }
    }

    Asrc = AsrcN; Bsrc = BsrcN; m0 = m0N; n0 = n0N; is_q = is_qN;
  }
#undef RESOLVE
#undef STAGE
#undef BARRIER
#undef LGKM0
#undef VM4
}

// ---------------- 128x64-tile out-projection GEMM (f32 out) ----------------
__global__ __launch_bounds__(256,4) void gemm_out(
    const u16* __restrict__ A, const u16* __restrict__ BT,
    float* __restrict__ C)
{
  __shared__ u16 lA[128*32];
  __shared__ u16 lB[64*32];
  const int tid = threadIdx.x;
  const int w = tid>>6, lane = tid&63;
  const int li = lane&15, lg = lane>>4;
  const int wm = w>>1, wn = w&1;    // 2M x 2N, wave-tile 64x32
  int m0 = blockIdx.y*128, n0 = blockIdx.x*64;
  const int srow = tid>>2;          // 0..63
  const int scol = ((tid&3) ^ ((tid>>3)&3))*8;
  const int rchunk = (lg ^ ((li>>1)&3))*8;
  u16* dA0 = lA + (w*16)*32;
  u16* dA1 = lA + (64 + w*16)*32;
  u16* dB  = lB + (w*16)*32;
  const u16* pa0 = A  + (size_t)(m0 + srow)*1024 + scol;
  const u16* pa1 = A  + (size_t)(m0 + 64 + srow)*1024 + scol;
  const u16* pb  = BT + (size_t)(n0 + srow)*1024 + scol;
  f32x4 acc[4][2] = {};
  for (int k=0; k<32; ++k) {
    gl_lds16(pa0 + k*32, dA0);
    gl_lds16(pa1 + k*32, dA1);
    if (srow < 64) gl_lds16(pb + k*32, dB);
    __syncthreads();
    bf16x8 af[4], bf[2];
    #pragma unroll
    for (int m=0;m<4;++m) af[m] = *(const bf16x8*)(lA + (wm*64 + m*16 + li)*32 + rchunk);
    #pragma unroll
    for (int n=0;n<2;++n) bf[n] = *(const bf16x8*)(lB + (wn*32 + n*16 + li)*32 + rchunk);
    #pragma unroll
    for (int m=0;m<4;++m)
      #pragma unroll
      for (int n=0;n<2;++n)
        acc[m][n] = __builtin_amdgcn_mfma_f32_16x16x32_bf16(af[m], bf[n], acc[m][n], 0,0,0);
    __syncthreads();
  }
  #pragma unroll
  for (int m=0;m<4;++m)
    #pragma unroll
    for (int n=0;n<2;++n) {
      int row = m0 + wm*64 + m*16 + lg*4;
      int col = n0 + wn*32 + n*16 + li;
      #pragma unroll
      for (int rg=0;rg<4;++rg)
        C[(size_t)(row+rg)*1024 + col] = acc[m][n][rg];
    }
}

// ---------------- MFMA flash attention, LDS-staged K/V (double-buffered) ----------------
__global__ __launch_bounds__(256,2) void attn_kernel(
    const u16* __restrict__ qbuf, const u16* __restrict__ kbuf,
    const u16* __restrict__ vT, u16* __restrict__ aout)
{
  __shared__ u16 kv_lds[2][2][64][64];   // 32 KB: [buf][K=0/V=1][row][64 elems]
  __shared__ u16 p_im[4][16][72];
  int blk = blockIdx.x;
  int bt = blk >> 4, h = blk & 15;
  int w = threadIdx.x>>6, lane = threadIdx.x&63;
  int li = lane&15, lg = lane>>4;
  const u16* qrow = qbuf + ((size_t)(bt*64 + w*16 + li))*1024 + h*64;
  bf16x8 qf0 = *(const bf16x8*)(qrow + lg*8);
  bf16x8 qf1 = *(const bf16x8*)(qrow + 32 + lg*8);
  const int srl = lane>>3;              // row-in-8
  const int sch = (lane&7) ^ srl;       // swizzled source chunk
  const u16* kgbase = kbuf + ((size_t)(bt*1088) + w*16 + srl)*1024 + h*64 + sch*8;
  const u16* vgbase = vT + ((size_t)(bt*1024 + h*64 + w*16 + srl))*1088 + sch*8;
  const int rc0 = ((lg     ^ (li&7)))*8;
  const int rc1 = (((4+lg) ^ (li&7)))*8;

#define STAGE_KV(b, c) do {                                                    \
    int _j0 = (c)*64;                                                          \
    _Pragma("unroll")                                                          \
    for (int i=0;i<2;++i) {                                                    \
      gl_lds16(kgbase + (size_t)(_j0 + i*8)*1024, &kv_lds[b][0][w*16+i*8][0]); \
      gl_lds16(vgbase + _j0 + (size_t)(i*8)*1088, &kv_lds[b][1][w*16+i*8][0]); \
    }                                                                          \
  } while(0)

  float mrun = -INFINITY, lrun = 0.f;
  f32x4 oacc[4] = {};

  STAGE_KV(0,0);
  __syncthreads();

  for (int c=0; c<17; ++c) {
    int cb = c&1;
    if (c<16) STAGE_KV(cb^1, c+1);
    const u16* kl = &kv_lds[cb][0][0][0];
    const u16* vl = &kv_lds[cb][1][0][0];
    f32x4 s[4] = {};
    #pragma unroll
    for (int jt=0; jt<4; ++jt) {
      const u16* kr = kl + (jt*16+li)*64;
      bf16x8 k0 = *(const bf16x8*)(kr + rc0);
      bf16x8 k1 = *(const bf16x8*)(kr + rc1);
      s[jt] = __builtin_amdgcn_mfma_f32_16x16x32_bf16(k0, qf0, s[jt], 0,0,0);
      s[jt] = __builtin_amdgcn_mfma_f32_16x16x32_bf16(k1, qf1, s[jt], 0,0,0);
    }
    float cm = -INFINITY;
    #pragma unroll
    for (int jt=0;jt<4;++jt)
      cm = fmaxf(cm, fmaxf(fmaxf(s[jt][0], s[jt][1]), fmaxf(s[jt][2], s[jt][3])));
    cm = fmaxf(cm, __shfl_xor(cm,16));
    cm = fmaxf(cm, __shfl_xor(cm,32));
    float mnew = fmaxf(mrun, cm);
    float sf = __expf(mrun - mnew);
    float ls = 0.f;
    #pragma unroll
    for (int jt=0;jt<4;++jt) {
      float p0 = __expf(s[jt][0]-mnew), p1 = __expf(s[jt][1]-mnew);
      float p2 = __expf(s[jt][2]-mnew), p3 = __expf(s[jt][3]-mnew);
      ls += p0+p1+p2+p3;
      ushort4 pk; pk.x = f2bf(p0); pk.y = f2bf(p1); pk.z = f2bf(p2); pk.w = f2bf(p3);
      *(ushort4*)&p_im[w][li][jt*16 + lg*4] = pk;
    }
    ls += __shfl_xor(ls,16);
    ls += __shfl_xor(ls,32);
    lrun = lrun*sf + ls;
    mrun = mnew;
    float sfr[4];
    #pragma unroll
    for (int rg=0;rg<4;++rg) sfr[rg] = __shfl(sf, lg*4+rg);
    #pragma unroll
    for (int dt=0;dt<4;++dt) {
      oacc[dt][0]*=sfr[0]; oacc[dt][1]*=sfr[1]; oacc[dt][2]*=sfr[2]; oacc[dt][3]*=sfr[3];
    }
    bf16x8 pa0 = *(const bf16x8*)&p_im[w][li][lg*8];
    bf16x8 pa1 = *(const bf16x8*)&p_im[w][li][32 + lg*8];
    #pragma unroll
    for (int dt=0;dt<4;++dt) {
      const u16* vr = vl + (dt*16+li)*64;
      bf16x8 v0 = *(const bf16x8*)(vr + rc0);
      bf16x8 v1 = *(const bf16x8*)(vr + rc1);
      oacc[dt] = __builtin_amdgcn_mfma_f32_16x16x32_bf16(pa0, v0, oacc[dt], 0,0,0);
      oacc[dt] = __builtin_amdgcn_mfma_f32_16x16x32_bf16(pa1, v1, oacc[dt], 0,0,0);
    }
    __syncthreads();
  }
#undef STAGE_KV

  float linv[4];
  #pragma unroll
  for (int rg=0;rg<4;++rg) linv[rg] = 1.f / __shfl(lrun, lg*4+rg);
  u16* orow = aout + ((size_t)(bt*64 + w*16))*1024 + h*64;
  #pragma unroll
  for (int dt=0;dt<4;++dt)
    #pragma unroll
    for (int rg=0;rg<4;++rg)
      orow[(size_t)(lg*4+rg)*1024 + dt*16 + li] = f2bf(oacc[dt][rg]*linv[rg]);
}

// ---------------- launch ----------------
extern "C" void kernel_launch(void* const* d_in, const int* in_sizes, int n_in,
                              void* d_out, int out_size, void* d_ws, size_t ws_size,
                              hipStream_t stream) {
  const float* x   = (const float*)d_in[0];
  const float* lat = (const float*)d_in[1];
  const float* gm  = (const float*)d_in[2];
  const float* bm  = (const float*)d_in[3];
  const float* gl  = (const float*)d_in[4];
  const float* bl  = (const float*)d_in[5];
  const float* Wq  = (const float*)d_in[6];
  const float* Wkv = (const float*)d_in[7];
  const float* Wo  = (const float*)d_in[8];
  float* out = (float*)d_out;

  char* ws = (char*)d_ws;
  const size_t KV_BYTES = (size_t)32*1088*1024*2;
  u16* kvin = (u16*)(ws);
  u16* kbuf = (u16*)(ws + KV_BYTES);
  u16* vT   = (u16*)(ws + 2*KV_BYTES);
  u16* latb = (u16*)(ws + 3*KV_BYTES);
  u16* qbuf = (u16*)(ws + 3*KV_BYTES + (size_t)4194304);
  u16* aout = (u16*)(ws + 3*KV_BYTES + (size_t)2*4194304);
  u16* wqT  = (u16*)(ws + 3*KV_BYTES + (size_t)3*4194304);
  u16* wkvT = (u16*)(ws + 3*KV_BYTES + (size_t)3*4194304 + 2097152);
  u16* woT  = (u16*)(ws + 3*KV_BYTES + (size_t)3*4194304 + 2097152 + 4194304);

  ln_tr_kernel<<<dim3(38912), dim3(256), 0, stream>>>(
      x, lat, gm, bm, gl, bl, Wq, Wkv, Wo, kvin, latb, wqT, wkvT, woT);

  gemm256_kvq<<<dim3(256), dim3(512), 0, stream>>>(kvin, wkvT, latb, wqT, kbuf, vT, qbuf);
  attn_kernel<<<dim3(512), dim3(256), 0, stream>>>(qbuf, kbuf, vT, aout);
  gemm_out<<<dim3(16,16), dim3(256), 0, stream>>>(aout, woT, out);
}

// Round 11
// 260.789 us; speedup vs baseline: 1.0231x; 1.0231x over previous
//
#include <hip/hip_runtime.h>

#define DEVI __device__ __forceinline__

typedef unsigned short u16;
typedef unsigned int u32;

using bf16x8 = __attribute__((ext_vector_type(8))) short;
using f32x4  = __attribute__((ext_vector_type(4))) float;

DEVI u16 f2bf(float f) {
  u32 u = __builtin_bit_cast(u32, f);
  u32 r = (u + 0x7fffu + ((u >> 16) & 1u)) >> 16;
  return (u16)r;
}

DEVI void gl_lds16(const u16* g, u16* l) {
  __builtin_amdgcn_global_load_lds(
      (const __attribute__((address_space(1))) u32*)g,
      (__attribute__((address_space(3))) u32*)l, 16, 0, 0);
}

// ---------------- LayerNorm + bf16 cast, fused with weight transposes ----------------
__global__ __launch_bounds__(256) void ln_tr_kernel(
    const float* __restrict__ x, const float* __restrict__ lat,
    const float* __restrict__ gm, const float* __restrict__ bm,
    const float* __restrict__ gl, const float* __restrict__ bl,
    const float* __restrict__ Wq, const float* __restrict__ Wkv,
    const float* __restrict__ Wo,
    u16* __restrict__ kvin, u16* __restrict__ latb,
    u16* __restrict__ wqT, u16* __restrict__ wkvT, u16* __restrict__ woT)
{
  __shared__ float tshm[32][33];
  __shared__ float red[2][4];
  if (blockIdx.x >= 34816) {
    int t = blockIdx.x - 34816;       // 0..4095
    int bxg = t & 127, gy = t >> 7;   // 128 x 32
    const float* in; u16* outp; int C, bxi;
    if (bxg < 32)      { in = Wq;  outp = wqT;  C = 1024; bxi = bxg; }
    else if (bxg < 96) { in = Wkv; outp = wkvT; C = 2048; bxi = bxg - 32; }
    else               { in = Wo;  outp = woT;  C = 1024; bxi = bxg - 96; }
    int bx = bxi*32, by = gy*32;
    int tx = threadIdx.x & 31, ty = threadIdx.x >> 5;   // 32 x 8
    for (int k=0;k<32;k+=8) tshm[ty+k][tx] = in[(size_t)(by+ty+k)*C + bx+tx];
    __syncthreads();
    for (int k=0;k<32;k+=8) outp[(size_t)(bx+ty+k)*1024 + by+tx] = f2bf(tshm[tx][ty+k]);
    return;
  }
  int row = blockIdx.x;
  int bt = row / 1088, r = row % 1088;
  const float *src, *g, *b;
  bool is_lat = (r >= 1024);
  if (!is_lat) { src = x + ((size_t)bt*1024 + r)*1024; g = gm; b = bm; }
  else         { src = lat + ((size_t)bt*64 + (r-1024))*1024; g = gl; b = bl; }
  int tid = threadIdx.x;
  float4 v = *(const float4*)(src + tid*4);
  float s1 = v.x+v.y+v.z+v.w;
  float s2 = v.x*v.x+v.y*v.y+v.z*v.z+v.w*v.w;
  for (int off=32; off; off>>=1){ s1 += __shfl_down(s1,off); s2 += __shfl_down(s2,off); }
  int w = tid>>6, lane = tid&63;
  if (lane==0){ red[0][w]=s1; red[1][w]=s2; }
  __syncthreads();
  s1 = red[0][0]+red[0][1]+red[0][2]+red[0][3];
  s2 = red[1][0]+red[1][1]+red[1][2]+red[1][3];
  float mu = s1 * (1.f/1024.f);
  float var = s2 * (1.f/1024.f) - mu*mu;
  float rstd = rsqrtf(var + 1e-5f);
  float4 gv = *(const float4*)(g + tid*4);
  float4 bv = *(const float4*)(b + tid*4);
  ushort4 o;
  o.x = f2bf((v.x-mu)*rstd*gv.x + bv.x);
  o.y = f2bf((v.y-mu)*rstd*gv.y + bv.y);
  o.z = f2bf((v.z-mu)*rstd*gv.z + bv.z);
  o.w = f2bf((v.w-mu)*rstd*gv.w + bv.w);
  *(ushort4*)(kvin + (size_t)row*1024 + tid*4) = o;
  if (is_lat) *(ushort4*)(latb + ((size_t)(bt*64 + (r-1024)))*1024 + tid*4) = o;
}

// ---------------- 256x256 4-phase bf16 GEMM: kv + q projections, tail-packed ----------------
// bid 0..1023 (full 256x256): swz<992 -> kv m-tiles 0..123; else 32 q tiles.
// bid 1024..1215 (half 128x256): kv rows 31744..34815 as 24 m-half-tiles x 8 n.
// Epilogue is fully unrolled with static acc indices (rule #20: no runtime bound).
__global__ __launch_bounds__(512,2) void gemm256_kvq(
    const u16* __restrict__ A, const u16* __restrict__ BT,
    const u16* __restrict__ Aq, const u16* __restrict__ BTq,
    u16* __restrict__ kb, u16* __restrict__ vt, u16* __restrict__ qb)
{
  __shared__ u16 lds[2][2][2][256][32];   // 128 KiB
  const int tid = threadIdx.x;
  const int w = tid>>6, lane = tid&63;
  const int li = lane&15, lg = lane>>4;
  const int wm = w>>2, wn = w&3;          // 2M x 4N waves
  const int bid = blockIdx.x;
  bool half = false, is_q = false;
  const u16 *Asrc, *Bsrc; int m0, n0;
  if (bid < 1024) {
    int swz = (bid&7)*128 + (bid>>3);     // bijective XCD swizzle (1024%8==0)
    if (swz < 992) { Asrc = A; Bsrc = BT; m0 = (swz>>3)*256; n0 = (swz&7)*256; }
    else { is_q = true; int qt = swz-992; Asrc = Aq; Bsrc = BTq; m0 = (qt>>2)*256; n0 = (qt&3)*256; }
  } else {
    int t = bid - 1024;                   // 0..191
    int swz = (t&7)*24 + (t>>3);          // bijective (192%8==0)
    half = true; Asrc = A; Bsrc = BT;
    m0 = 31744 + (swz>>3)*128; n0 = (swz&7)*256;
  }
  const int wrowbase = half ? wm*64 : wm*128;   // wave's A-row base in LDS/tile
  const int srow = lane>>2;
  const int scol = ((lane&3) ^ ((lane>>3)&3))*8;  // source-side T2 involution
  const int rchunk = (lg ^ ((li>>1)&3))*8;        // read-side (same involution)

  // NOTE: for half tiles STAGE still loads 256 A-rows (rows 128..255 are garbage,
  // never read as A; global over-read lands in kbuf -- allocated, harmless).
#define STAGE(b, mat, kh, kt) do {                                            \
    const u16* _s = (mat) ? Bsrc : Asrc;                                      \
    const int _base = (mat) ? n0 : m0;                                        \
    _Pragma("unroll")                                                         \
    for (int L=0; L<2; ++L) {                                                 \
      const int _r = L*128 + w*16;                                            \
      gl_lds16(_s + (size_t)(_base + _r + srow)*1024 + (kt)*64 + (kh)*32 + scol, \
               &lds[b][mat][kh][_r][0]);                                      \
    }                                                                         \
  } while(0)
#define BARRIER() asm volatile("s_barrier" ::: "memory")
#define LGKM0()   do { asm volatile("s_waitcnt lgkmcnt(0)" ::: "memory"); \
                       __builtin_amdgcn_sched_barrier(0); } while(0)
#define VM4()     asm volatile("s_waitcnt vmcnt(4)" ::: "memory")

  f32x4 acc[8][4] = {};

  STAGE(0,0,0,0); STAGE(0,1,0,0); STAGE(0,0,1,0); STAGE(0,1,1,0);
  VM4(); BARRIER();

  for (int j=0; j<16; ++j) {
    const int c = j&1;
    const int kt = (j<15) ? j+1 : 15;
    bf16x8 a[4], b0[4], b1[4];

    // ---- phase 0: kh0, mh0 ----
    #pragma unroll
    for (int mf=0; mf<4; ++mf)
      a[mf] = *(const bf16x8*)&lds[c][0][0][wrowbase + mf*16 + li][rchunk];
    #pragma unroll
    for (int nf=0; nf<4; ++nf)
      b0[nf] = *(const bf16x8*)&lds[c][1][0][wn*64 + nf*16 + li][rchunk];
    STAGE(c^1,0,0,kt);
    BARRIER(); LGKM0();
    __builtin_amdgcn_s_setprio(1);
    #pragma unroll
    for (int mf=0; mf<4; ++mf)
      #pragma unroll
      for (int nf=0; nf<4; ++nf)
        acc[mf][nf] = __builtin_amdgcn_mfma_f32_16x16x32_bf16(a[mf], b0[nf], acc[mf][nf], 0,0,0);
    __builtin_amdgcn_s_setprio(0);
    BARRIER();

    // ---- phase 1: kh0, mh1 (full tiles only; uniform branch, static indices) ----
    if (!half) {
      #pragma unroll
      for (int mf=0; mf<4; ++mf)
        a[mf] = *(const bf16x8*)&lds[c][0][0][wrowbase + 64 + mf*16 + li][rchunk];
    }
    STAGE(c^1,1,0,kt);
    VM4();
    BARRIER(); LGKM0();
    if (!half) {
      __builtin_amdgcn_s_setprio(1);
      #pragma unroll
      for (int mf=0; mf<4; ++mf)
        #pragma unroll
        for (int nf=0; nf<4; ++nf)
          acc[4+mf][nf] = __builtin_amdgcn_mfma_f32_16x16x32_bf16(a[mf], b0[nf], acc[4+mf][nf], 0,0,0);
      __builtin_amdgcn_s_setprio(0);
    }
    BARRIER();

    // ---- phase 2: kh1, mh0 ----
    #pragma unroll
    for (int mf=0; mf<4; ++mf)
      a[mf] = *(const bf16x8*)&lds[c][0][1][wrowbase + mf*16 + li][rchunk];
    #pragma unroll
    for (int nf=0; nf<4; ++nf)
      b1[nf] = *(const bf16x8*)&lds[c][1][1][wn*64 + nf*16 + li][rchunk];
    STAGE(c^1,0,1,kt);
    BARRIER(); LGKM0();
    __builtin_amdgcn_s_setprio(1);
    #pragma unroll
    for (int mf=0; mf<4; ++mf)
      #pragma unroll
      for (int nf=0; nf<4; ++nf)
        acc[mf][nf] = __builtin_amdgcn_mfma_f32_16x16x32_bf16(a[mf], b1[nf], acc[mf][nf], 0,0,0);
    __builtin_amdgcn_s_setprio(0);
    BARRIER();

    // ---- phase 3: kh1, mh1 (full tiles only) ----
    if (!half) {
      #pragma unroll
      for (int mf=0; mf<4; ++mf)
        a[mf] = *(const bf16x8*)&lds[c][0][1][wrowbase + 64 + mf*16 + li][rchunk];
    }
    STAGE(c^1,1,1,kt);
    VM4();
    BARRIER(); LGKM0();
    if (!half) {
      __builtin_amdgcn_s_setprio(1);
      #pragma unroll
      for (int mf=0; mf<4; ++mf)
        #pragma unroll
        for (int nf=0; nf<4; ++nf)
          acc[4+mf][nf] = __builtin_amdgcn_mfma_f32_16x16x32_bf16(a[mf], b1[nf], acc[4+mf][nf], 0,0,0);
      __builtin_amdgcn_s_setprio(0);
    }
    BARRIER();
  }
#undef STAGE
#undef BARRIER
#undef LGKM0
#undef VM4

  // epilogue: fully unrolled, static acc indices; runtime-uniform guards only
  if (is_q) {
    #pragma unroll
    for (int am=0; am<8; ++am)
      #pragma unroll
      for (int nf=0; nf<4; ++nf) {
        int row = m0 + wm*128 + am*16 + lg*4;
        int col = n0 + wn*64 + nf*16 + li;
        #pragma unroll
        for (int rg=0; rg<4; ++rg)
          qb[(size_t)(row+rg)*1024 + col] = f2bf(acc[am][nf][rg]*0.125f);
      }
  } else if (n0 < 1024) {
    #pragma unroll
    for (int am=0; am<8; ++am) {
      if (half && am >= 4) continue;   // uniform guard; am is compile-time
      #pragma unroll
      for (int nf=0; nf<4; ++nf) {
        int row = m0 + wrowbase + am*16 + lg*4;
        int col = n0 + wn*64 + nf*16 + li;
        #pragma unroll
        for (int rg=0; rg<4; ++rg)
          kb[(size_t)(row+rg)*1024 + col] = f2bf(acc[am][nf][rg]);
      }
    }
  } else {
    #pragma unroll
    for (int am=0; am<8; ++am) {
      if (half && am >= 4) continue;
      #pragma unroll
      for (int nf=0; nf<4; ++nf) {
        int r0 = m0 + wrowbase + am*16 + lg*4;
        int cc = n0 + wn*64 + nf*16 + li - 1024;
        int bt = r0/1088, jj = r0 - bt*1088;
        ushort4 o;
        o.x = f2bf(acc[am][nf][0]); o.y = f2bf(acc[am][nf][1]);
        o.z = f2bf(acc[am][nf][2]); o.w = f2bf(acc[am][nf][3]);
        *(ushort4*)(vt + ((size_t)(bt*1024 + cc))*1088 + jj) = o;
      }
    }
  }
}

// ---------------- 128x64-tile out-projection GEMM (f32 out) ----------------
__global__ __launch_bounds__(256,4) void gemm_out(
    const u16* __restrict__ A, const u16* __restrict__ BT,
    float* __restrict__ C)
{
  __shared__ u16 lA[128*32];
  __shared__ u16 lB[64*32];
  const int tid = threadIdx.x;
  const int w = tid>>6, lane = tid&63;
  const int li = lane&15, lg = lane>>4;
  const int wm = w>>1, wn = w&1;    // 2M x 2N, wave-tile 64x32
  int m0 = blockIdx.y*128, n0 = blockIdx.x*64;
  const int srow = tid>>2;          // 0..63
  const int scol = ((tid&3) ^ ((tid>>3)&3))*8;
  const int rchunk = (lg ^ ((li>>1)&3))*8;
  u16* dA0 = lA + (w*16)*32;
  u16* dA1 = lA + (64 + w*16)*32;
  u16* dB  = lB + (w*16)*32;
  const u16* pa0 = A  + (size_t)(m0 + srow)*1024 + scol;
  const u16* pa1 = A  + (size_t)(m0 + 64 + srow)*1024 + scol;
  const u16* pb  = BT + (size_t)(n0 + srow)*1024 + scol;
  f32x4 acc[4][2] = {};
  for (int k=0; k<32; ++k) {
    gl_lds16(pa0 + k*32, dA0);
    gl_lds16(pa1 + k*32, dA1);
    if (srow < 64) gl_lds16(pb + k*32, dB);
    __syncthreads();
    bf16x8 af[4], bf[2];
    #pragma unroll
    for (int m=0;m<4;++m) af[m] = *(const bf16x8*)(lA + (wm*64 + m*16 + li)*32 + rchunk);
    #pragma unroll
    for (int n=0;n<2;++n) bf[n] = *(const bf16x8*)(lB + (wn*32 + n*16 + li)*32 + rchunk);
    #pragma unroll
    for (int m=0;m<4;++m)
      #pragma unroll
      for (int n=0;n<2;++n)
        acc[m][n] = __builtin_amdgcn_mfma_f32_16x16x32_bf16(af[m], bf[n], acc[m][n], 0,0,0);
    __syncthreads();
  }
  #pragma unroll
  for (int m=0;m<4;++m)
    #pragma unroll
    for (int n=0;n<2;++n) {
      int row = m0 + wm*64 + m*16 + lg*4;
      int col = n0 + wn*32 + n*16 + li;
      #pragma unroll
      for (int rg=0;rg<4;++rg)
        C[(size_t)(row+rg)*1024 + col] = acc[m][n][rg];
    }
}

// ---------------- MFMA flash attention, LDS-staged K/V (double-buffered) ----------------
__global__ __launch_bounds__(256,2) void attn_kernel(
    const u16* __restrict__ qbuf, const u16* __restrict__ kbuf,
    const u16* __restrict__ vT, u16* __restrict__ aout)
{
  __shared__ u16 kv_lds[2][2][64][64];   // 32 KB: [buf][K=0/V=1][row][64 elems]
  __shared__ u16 p_im[4][16][72];
  int blk = blockIdx.x;
  int bt = blk >> 4, h = blk & 15;
  int w = threadIdx.x>>6, lane = threadIdx.x&63;
  int li = lane&15, lg = lane>>4;
  const u16* qrow = qbuf + ((size_t)(bt*64 + w*16 + li))*1024 + h*64;
  bf16x8 qf0 = *(const bf16x8*)(qrow + lg*8);
  bf16x8 qf1 = *(const bf16x8*)(qrow + 32 + lg*8);
  const int srl = lane>>3;              // row-in-8
  const int sch = (lane&7) ^ srl;       // swizzled source chunk
  const u16* kgbase = kbuf + ((size_t)(bt*1088) + w*16 + srl)*1024 + h*64 + sch*8;
  const u16* vgbase = vT + ((size_t)(bt*1024 + h*64 + w*16 + srl))*1088 + sch*8;
  const int rc0 = ((lg     ^ (li&7)))*8;
  const int rc1 = (((4+lg) ^ (li&7)))*8;

#define STAGE_KV(b, c) do {                                                    \
    int _j0 = (c)*64;                                                          \
    _Pragma("unroll")                                                          \
    for (int i=0;i<2;++i) {                                                    \
      gl_lds16(kgbase + (size_t)(_j0 + i*8)*1024, &kv_lds[b][0][w*16+i*8][0]); \
      gl_lds16(vgbase + _j0 + (size_t)(i*8)*1088, &kv_lds[b][1][w*16+i*8][0]); \
    }                                                                          \
  } while(0)

  float mrun = -INFINITY, lrun = 0.f;
  f32x4 oacc[4] = {};

  STAGE_KV(0,0);
  __syncthreads();

  for (int c=0; c<17; ++c) {
    int cb = c&1;
    if (c<16) STAGE_KV(cb^1, c+1);
    const u16* kl = &kv_lds[cb][0][0][0];
    const u16* vl = &kv_lds[cb][1][0][0];
    f32x4 s[4] = {};
    #pragma unroll
    for (int jt=0; jt<4; ++jt) {
      const u16* kr = kl + (jt*16+li)*64;
      bf16x8 k0 = *(const bf16x8*)(kr + rc0);
      bf16x8 k1 = *(const bf16x8*)(kr + rc1);
      s[jt] = __builtin_amdgcn_mfma_f32_16x16x32_bf16(k0, qf0, s[jt], 0,0,0);
      s[jt] = __builtin_amdgcn_mfma_f32_16x16x32_bf16(k1, qf1, s[jt], 0,0,0);
    }
    float cm = -INFINITY;
    #pragma unroll
    for (int jt=0;jt<4;++jt)
      cm = fmaxf(cm, fmaxf(fmaxf(s[jt][0], s[jt][1]), fmaxf(s[jt][2], s[jt][3])));
    cm = fmaxf(cm, __shfl_xor(cm,16));
    cm = fmaxf(cm, __shfl_xor(cm,32));
    float mnew = fmaxf(mrun, cm);
    float sf = __expf(mrun - mnew);
    float ls = 0.f;
    #pragma unroll
    for (int jt=0;jt<4;++jt) {
      float p0 = __expf(s[jt][0]-mnew), p1 = __expf(s[jt][1]-mnew);
      float p2 = __expf(s[jt][2]-mnew), p3 = __expf(s[jt][3]-mnew);
      ls += p0+p1+p2+p3;
      ushort4 pk; pk.x = f2bf(p0); pk.y = f2bf(p1); pk.z = f2bf(p2); pk.w = f2bf(p3);
      *(ushort4*)&p_im[w][li][jt*16 + lg*4] = pk;
    }
    ls += __shfl_xor(ls,16);
    ls += __shfl_xor(ls,32);
    lrun = lrun*sf + ls;
    mrun = mnew;
    float sfr[4];
    #pragma unroll
    for (int rg=0;rg<4;++rg) sfr[rg] = __shfl(sf, lg*4+rg);
    #pragma unroll
    for (int dt=0;dt<4;++dt) {
      oacc[dt][0]*=sfr[0]; oacc[dt][1]*=sfr[1]; oacc[dt][2]*=sfr[2]; oacc[dt][3]*=sfr[3];
    }
    bf16x8 pa0 = *(const bf16x8*)&p_im[w][li][lg*8];
    bf16x8 pa1 = *(const bf16x8*)&p_im[w][li][32 + lg*8];
    #pragma unroll
    for (int dt=0;dt<4;++dt) {
      const u16* vr = vl + (dt*16+li)*64;
      bf16x8 v0 = *(const bf16x8*)(vr + rc0);
      bf16x8 v1 = *(const bf16x8*)(vr + rc1);
      oacc[dt] = __builtin_amdgcn_mfma_f32_16x16x32_bf16(pa0, v0, oacc[dt], 0,0,0);
      oacc[dt] = __builtin_amdgcn_mfma_f32_16x16x32_bf16(pa1, v1, oacc[dt], 0,0,0);
    }
    __syncthreads();
  }
#undef STAGE_KV

  float linv[4];
  #pragma unroll
  for (int rg=0;rg<4;++rg) linv[rg] = 1.f / __shfl(lrun, lg*4+rg);
  u16* orow = aout + ((size_t)(bt*64 + w*16))*1024 + h*64;
  #pragma unroll
  for (int dt=0;dt<4;++dt)
    #pragma unroll
    for (int rg=0;rg<4;++rg)
      orow[(size_t)(lg*4+rg)*1024 + dt*16 + li] = f2bf(oacc[dt][rg]*linv[rg]);
}

// ---------------- launch ----------------
extern "C" void kernel_launch(void* const* d_in, const int* in_sizes, int n_in,
                              void* d_out, int out_size, void* d_ws, size_t ws_size,
                              hipStream_t stream) {
  const float* x   = (const float*)d_in[0];
  const float* lat = (const float*)d_in[1];
  const float* gm  = (const float*)d_in[2];
  const float* bm  = (const float*)d_in[3];
  const float* gl  = (const float*)d_in[4];
  const float* bl  = (const float*)d_in[5];
  const float* Wq  = (const float*)d_in[6];
  const float* Wkv = (const float*)d_in[7];
  const float* Wo  = (const float*)d_in[8];
  float* out = (float*)d_out;

  char* ws = (char*)d_ws;
  const size_t KV_BYTES = (size_t)32*1088*1024*2;
  u16* kvin = (u16*)(ws);
  u16* kbuf = (u16*)(ws + KV_BYTES);
  u16* vT   = (u16*)(ws + 2*KV_BYTES);
  u16* latb = (u16*)(ws + 3*KV_BYTES);
  u16* qbuf = (u16*)(ws + 3*KV_BYTES + (size_t)4194304);
  u16* aout = (u16*)(ws + 3*KV_BYTES + (size_t)2*4194304);
  u16* wqT  = (u16*)(ws + 3*KV_BYTES + (size_t)3*4194304);
  u16* wkvT = (u16*)(ws + 3*KV_BYTES + (size_t)3*4194304 + 2097152);
  u16* woT  = (u16*)(ws + 3*KV_BYTES + (size_t)3*4194304 + 2097152 + 4194304);

  ln_tr_kernel<<<dim3(38912), dim3(256), 0, stream>>>(
      x, lat, gm, bm, gl, bl, Wq, Wkv, Wo, kvin, latb, wqT, wkvT, woT);

  gemm256_kvq<<<dim3(1216), dim3(512), 0, stream>>>(kvin, wkvT, latb, wqT, kbuf, vT, qbuf);
  attn_kernel<<<dim3(512), dim3(256), 0, stream>>>(qbuf, kbuf, vT, aout);
  gemm_out<<<dim3(16,16), dim3(256), 0, stream>>>(aout, woT, out);
}